// Round 6
// baseline (273.882 us; speedup 1.0000x reference)
//
#include <hip/hip_runtime.h>

#define DIM 128
#define EPB_A 2048   // edges per block in histscat (8/thread)
#define CAP 5120     // per-bucket slab capacity (mean 4092, +16 sigma)
#define NBMAX 512

// ---------- bf16 helpers ----------
__device__ __forceinline__ float bf_lo(unsigned u) { return __uint_as_float(u << 16); }
__device__ __forceinline__ float bf_hi(unsigned u) { return __uint_as_float(u & 0xffff0000u); }
__device__ __forceinline__ unsigned short f2bf(float f) {
    unsigned u = __float_as_uint(f);
    u += 0x7fff + ((u >> 16) & 1);   // round-to-nearest-even
    return (unsigned short)(u >> 16);
}
__device__ __forceinline__ unsigned packbf(float a, float b) {
    return (unsigned)f2bf(a) | ((unsigned)f2bf(b) << 16);
}

#if __has_builtin(__builtin_amdgcn_fdot2_f32_bf16)
#define HAVE_DOT2 1
typedef __bf16 bf16x2 __attribute__((ext_vector_type(2)));
__device__ __forceinline__ float dot2bf(unsigned ab, unsigned nn, float acc) {
    return __builtin_amdgcn_fdot2_f32_bf16(
        __builtin_bit_cast(bf16x2, ab), __builtin_bit_cast(bf16x2, nn), acc, false);
}
#else
#define HAVE_DOT2 0
#endif

// ---------- build phase ----------

// Single global read of edges; LDS bucket-sort; coalesced slab writes.
__global__ __launch_bounds__(256) void histscat(const int2* __restrict__ edges, int E,
                                                int* __restrict__ deg,
                                                int* __restrict__ bcnt,
                                                unsigned* __restrict__ ebuck, int NB) {
    __shared__ unsigned ent[EPB_A];          // sorted packed entries (8 KB)
    __shared__ unsigned short sbkt[EPB_A];   // slot -> bucket (4 KB)
    __shared__ int lstart[NBMAX];            // local run starts (2 KB)
    __shared__ int fillo[NBMAX];             // counts, then fill cursors (2 KB)
    __shared__ int gbase[NBMAX];             // global run bases (2 KB)
    __shared__ int psum[256];                // scan scratch (1 KB)
    int tid = threadIdx.x;
    int base = blockIdx.x * EPB_A;
    int cnt = min(EPB_A, E - base);

    fillo[2 * tid] = 0; fillo[2 * tid + 1] = 0;
    __syncthreads();

    // read 8 edges/thread into registers (coalesced), histogram + out-degree
    int2 ed[8];
    #pragma unroll
    for (int i = 0; i < 8; ++i) {
        int idx = tid + i * 256;
        ed[i] = (idx < cnt) ? edges[base + idx] : make_int2(-1, -1);
    }
    #pragma unroll
    for (int i = 0; i < 8; ++i) {
        if (ed[i].x >= 0) {
            atomicAdd(&fillo[ed[i].y >> 8], 1);
            atomicAdd(&deg[ed[i].x], 1);
        }
    }
    __syncthreads();

    // exclusive scan over NBMAX buckets (2 per thread)
    int c0 = fillo[2 * tid], c1 = fillo[2 * tid + 1];
    int ps = c0 + c1;
    psum[tid] = ps;
    __syncthreads();
    for (int off = 1; off < 256; off <<= 1) {
        int t = (tid >= off) ? psum[tid - off] : 0;
        __syncthreads();
        psum[tid] += t;
        __syncthreads();
    }
    int excl = psum[tid] - ps;
    lstart[2 * tid] = excl;
    lstart[2 * tid + 1] = excl + c0;
    fillo[2 * tid] = excl;          // fill cursors = lstart
    fillo[2 * tid + 1] = excl + c0;
    // reserve contiguous global runs in bucket slabs
    if (2 * tid < NB && c0 > 0)     gbase[2 * tid]     = atomicAdd(&bcnt[2 * tid], c0);
    if (2 * tid + 1 < NB && c1 > 0) gbase[2 * tid + 1] = atomicAdd(&bcnt[2 * tid + 1], c1);
    __syncthreads();

    // scatter into sorted LDS order
    #pragma unroll
    for (int i = 0; i < 8; ++i) {
        if (ed[i].x >= 0) {
            int bkt = ed[i].y >> 8;
            int p = atomicAdd(&fillo[bkt], 1);
            ent[p] = ((unsigned)ed[i].x << 8) | (unsigned)(ed[i].y & 255);
            sbkt[p] = (unsigned short)bkt;
        }
    }
    __syncthreads();

    // coalesced write-out: adjacent slots share buckets -> contiguous addresses
    for (int j = tid; j < cnt; j += 256) {
        int bkt = sbkt[j];
        ebuck[(size_t)bkt * CAP + gbase[bkt] + (j - lstart[bkt])] = ent[j];
    }
}

// fp32 -> bf16 rows pre-scaled by dinv[node]; also stores dinv.
__global__ void conv_scaled(const float4* __restrict__ xin, const int* __restrict__ deg,
                            float* __restrict__ dinv, uint4* __restrict__ xout, int n8) {
    int i = blockIdx.x * blockDim.x + threadIdx.x;
    if (i < n8) {
        int node = i >> 4;   // 16 threads x 8 dims = 128
        float dv = rsqrtf((float)(deg[node] + 1));
        if ((i & 15) == 0) dinv[node] = dv;
        float4 v0 = xin[2 * i], v1 = xin[2 * i + 1];
        uint4 o;
        o.x = packbf(dv * v0.x, dv * v0.y); o.y = packbf(dv * v0.z, dv * v0.w);
        o.z = packbf(dv * v1.x, dv * v1.y); o.w = packbf(dv * v1.z, dv * v1.w);
        xout[i] = o;
    }
}

// Exclusive scan of bucket counts -> edge_base; rowoff terminator.
__global__ __launch_bounds__(512) void scanB(const int* __restrict__ bcnt,
                                             int* __restrict__ edge_base,
                                             int* __restrict__ rowoff,
                                             int NB, int E, int N) {
    __shared__ int s[512];
    int tid = threadIdx.x;
    int val = (tid < NB) ? bcnt[tid] : 0;
    s[tid] = val;
    __syncthreads();
    for (int off = 1; off < 512; off <<= 1) {
        int t = (tid >= off) ? s[tid - off] : 0;
        __syncthreads();
        s[tid] += t;
        __syncthreads();
    }
    if (tid < NB) edge_base[tid] = s[tid] - val;
    if (tid == NB - 1) edge_base[NB] = s[tid];   // == E
    if (tid == 0) rowoff[N] = E + N;
}

// One block per bucket (256 nodes): exact CSR segment + rowoff.
__global__ __launch_bounds__(256) void passC(const unsigned* __restrict__ ebuck,
                                             const int* __restrict__ edge_base,
                                             int* __restrict__ rowoff,
                                             int* __restrict__ csr_src, int N) {
    __shared__ int cnt[256], sbuf[256], fill[256];
    int b = blockIdx.x, tid = threadIdx.x;
    int eb0 = edge_base[b];
    int m = edge_base[b + 1] - eb0;
    const unsigned* eb = ebuck + (size_t)b * CAP;
    cnt[tid] = 0;
    __syncthreads();
    for (int i = tid; i < m; i += 256)
        atomicAdd(&cnt[eb[i] & 255u], 1);
    __syncthreads();
    int node = (b << 8) + tid;
    bool valid = node < N;
    int val = valid ? cnt[tid] + 1 : 0;   // +1 self-loop
    sbuf[tid] = val;
    __syncthreads();
    for (int off = 1; off < 256; off <<= 1) {
        int t = (tid >= off) ? sbuf[tid - off] : 0;
        __syncthreads();
        sbuf[tid] += t;
        __syncthreads();
    }
    int excl = sbuf[tid] - val;
    int csrb = eb0 + (b << 8);   // edges before + self-loops before
    if (valid) rowoff[node] = csrb + excl;
    fill[tid] = excl;
    __syncthreads();
    for (int i = tid; i < m; i += 256) {
        unsigned u = eb[i];
        int p = atomicAdd(&fill[u & 255u], 1);
        csr_src[csrb + p] = (int)(u >> 8);
    }
    __syncthreads();
    if (valid) csr_src[csrb + excl + cnt[tid]] = node;   // self-loop last
}

// ---------- layer: 1 wave/node, 16 lanes x 16B, 4 groups, 4-deep row pipeline ----

#define SEL_LO 0x05040100u
#define SEL_HI 0x07060302u
#define NN11   0x3F803F80u   // bf16 (1.0, 1.0)

#define ACC8ADD(c)                                      \
    a0 += bf_lo(c.x); a1 += bf_hi(c.x);                 \
    a2 += bf_lo(c.y); a3 += bf_hi(c.y);                 \
    a4 += bf_lo(c.z); a5 += bf_hi(c.z);                 \
    a6 += bf_lo(c.w); a7 += bf_hi(c.w);

#if HAVE_DOT2
#define ACCPAIR(cA, cB)                                                   \
    a0 = dot2bf(__builtin_amdgcn_perm(cB.x, cA.x, SEL_LO), NN11, a0);     \
    a1 = dot2bf(__builtin_amdgcn_perm(cB.x, cA.x, SEL_HI), NN11, a1);     \
    a2 = dot2bf(__builtin_amdgcn_perm(cB.y, cA.y, SEL_LO), NN11, a2);     \
    a3 = dot2bf(__builtin_amdgcn_perm(cB.y, cA.y, SEL_HI), NN11, a3);     \
    a4 = dot2bf(__builtin_amdgcn_perm(cB.z, cA.z, SEL_LO), NN11, a4);     \
    a5 = dot2bf(__builtin_amdgcn_perm(cB.z, cA.z, SEL_HI), NN11, a5);     \
    a6 = dot2bf(__builtin_amdgcn_perm(cB.w, cA.w, SEL_LO), NN11, a6);     \
    a7 = dot2bf(__builtin_amdgcn_perm(cB.w, cA.w, SEL_HI), NN11, a7);
#else
#define ACCPAIR(cA, cB) { ACC8ADD(cA); ACC8ADD(cB); }
#endif

__global__ __launch_bounds__(256) void gcn_layer(
    const uint4* __restrict__ yin, const int* __restrict__ rowoff,
    const int* __restrict__ csr_src, const float* __restrict__ dinv,
    const float* __restrict__ w, const float* __restrict__ bia,
    void* __restrict__ xout, int N, int mode) {
    int node = blockIdx.x * 4 + (threadIdx.x >> 6);
    if (node >= N) return;
    int lane = threadIdx.x & 63;
    int h  = lane >> 4;   // 4 concurrent edge groups
    int ln = lane & 15;   // 16 lanes x uint4(16B) = 256B row
    int start = rowoff[node], end = rowoff[node + 1];
    float a0=0,a1=0,a2=0,a3=0,a4=0,a5=0,a6=0,a7=0;

    int base = start + h;            // this group's edges: base + 4*j
    int mm = end - base;
    int m = (mm > 0) ? ((mm + 3) >> 2) : 0;   // edges this group handles
    int Q = m >> 2;                  // full quads (4 edges each)
    uint4 r0, r1, r2, r3;            // rows in flight for current quad
    int s0n = 0, s1n = 0, s2n = 0, s3n = 0;   // srcs for next quad
    if (Q > 0) {
        int i0 = csr_src[base], i1 = csr_src[base + 4];
        int i2 = csr_src[base + 8], i3 = csr_src[base + 12];
        r0 = yin[(size_t)i0 * 16 + ln];
        r1 = yin[(size_t)i1 * 16 + ln];
        r2 = yin[(size_t)i2 * 16 + ln];
        r3 = yin[(size_t)i3 * 16 + ln];
        if (Q > 1) {
            s0n = csr_src[base + 16]; s1n = csr_src[base + 20];
            s2n = csr_src[base + 24]; s3n = csr_src[base + 28];
        }
    }
    for (int q = 0; q < Q; ++q) {
        uint4 c0 = r0, c1 = r1, c2 = r2, c3 = r3;
        if (q + 1 < Q) {   // issue next quad's 4 row loads immediately
            r0 = yin[(size_t)s0n * 16 + ln];
            r1 = yin[(size_t)s1n * 16 + ln];
            r2 = yin[(size_t)s2n * 16 + ln];
            r3 = yin[(size_t)s3n * 16 + ln];
            if (q + 2 < Q) {   // srcs two quads ahead
                int o = base + 16 * (q + 2);
                s0n = csr_src[o]; s1n = csr_src[o + 4];
                s2n = csr_src[o + 8]; s3n = csr_src[o + 12];
            }
        }
        ACCPAIR(c0, c1);
        ACCPAIR(c2, c3);
    }
    // tail: up to 3 edges at base + 16Q + 4t
    for (int t = 0; t < (m & 3); ++t) {
        int s = csr_src[base + 16 * Q + 4 * t];
        uint4 c = yin[(size_t)s * 16 + ln];
        ACC8ADD(c);
    }

    float dn = dinv[node];
    a0+=__shfl_xor(a0,16); a1+=__shfl_xor(a1,16); a2+=__shfl_xor(a2,16); a3+=__shfl_xor(a3,16);
    a4+=__shfl_xor(a4,16); a5+=__shfl_xor(a5,16); a6+=__shfl_xor(a6,16); a7+=__shfl_xor(a7,16);
    a0+=__shfl_xor(a0,32); a1+=__shfl_xor(a1,32); a2+=__shfl_xor(a2,32); a3+=__shfl_xor(a3,32);
    a4+=__shfl_xor(a4,32); a5+=__shfl_xor(a5,32); a6+=__shfl_xor(a6,32); a7+=__shfl_xor(a7,32);

    if (h == 0) {
        float4 w0 = ((const float4*)w)[ln * 2],   w1 = ((const float4*)w)[ln * 2 + 1];
        float4 b0 = ((const float4*)bia)[ln * 2], b1 = ((const float4*)bia)[ln * 2 + 1];
        float o0 = fmaf(a0, dn * w0.x, b0.x), o1 = fmaf(a1, dn * w0.y, b0.y);
        float o2 = fmaf(a2, dn * w0.z, b0.z), o3 = fmaf(a3, dn * w0.w, b0.w);
        float o4 = fmaf(a4, dn * w1.x, b1.x), o5 = fmaf(a5, dn * w1.y, b1.y);
        float o6 = fmaf(a6, dn * w1.z, b1.z), o7 = fmaf(a7, dn * w1.w, b1.w);
        if (mode) {   // relu, pre-scale by dinv for next layer, bf16 out
            o0 = dn * fmaxf(o0, 0.f); o1 = dn * fmaxf(o1, 0.f);
            o2 = dn * fmaxf(o2, 0.f); o3 = dn * fmaxf(o3, 0.f);
            o4 = dn * fmaxf(o4, 0.f); o5 = dn * fmaxf(o5, 0.f);
            o6 = dn * fmaxf(o6, 0.f); o7 = dn * fmaxf(o7, 0.f);
            uint4 ov;
            ov.x = packbf(o0, o1); ov.y = packbf(o2, o3);
            ov.z = packbf(o4, o5); ov.w = packbf(o6, o7);
            ((uint4*)xout)[(size_t)node * 16 + ln] = ov;
        } else {      // fp32 out
            ((float4*)xout)[(size_t)node * 32 + ln * 2]     = make_float4(o0, o1, o2, o3);
            ((float4*)xout)[(size_t)node * 32 + ln * 2 + 1] = make_float4(o4, o5, o6, o7);
        }
    }
}

// ---------- launch ----------

static inline size_t align256(size_t x) { return (x + 255) & ~(size_t)255; }

extern "C" void kernel_launch(void* const* d_in, const int* in_sizes, int n_in,
                              void* d_out, int out_size, void* d_ws, size_t ws_size,
                              hipStream_t stream) {
    const int2*  edges = (const int2*)d_in[0];
    const float* x     = (const float*)d_in[1];
    const float* w1    = (const float*)d_in[2];
    const float* b1    = (const float*)d_in[3];
    const float* w2    = (const float*)d_in[4];
    const float* b2    = (const float*)d_in[5];
    float* out = (float*)d_out;

    const int E = in_sizes[0] / 2;
    const int N = in_sizes[1] / DIM;
    const int TOT = E + N;
    const int NB   = (N + 255) >> 8;            // dst buckets of 256 nodes
    const int nblk = (E + EPB_A - 1) / EPB_A;   // histscat blocks

    // workspace carve-up
    char* p = (char*)d_ws;
    int*      deg       = (int*)p;       // N, zeroed
    int*      bcnt      = deg + N;       // NB, zeroed (contiguous with deg)
    p += align256(((size_t)N + NB) * 4);
    float*    dinv      = (float*)p;     p += align256((size_t)N * 4);
    int*      edge_base = (int*)p;       p += align256((size_t)(NB + 1) * 4);
    int*      rowoff    = (int*)p;       p += align256((size_t)(N + 1) * 4);
    unsigned* ebuck     = (unsigned*)p;  p += align256((size_t)NB * CAP * 4);
    int*      csr_src   = (int*)p;       p += align256((size_t)TOT * 4);
    uint4*    yb        = (uint4*)p;     p += align256((size_t)N * DIM * 2);
    uint4*    hb        = (uint4*)p;     p += align256((size_t)N * DIM * 2);

    const int TPB = 256;
    int n8  = N * DIM / 8;
    int nbC = (n8 + TPB - 1) / TPB;

    hipMemsetAsync(deg, 0, ((size_t)N + NB) * 4, stream);
    histscat<<<nblk, TPB, 0, stream>>>(edges, E, deg, bcnt, ebuck, NB);
    conv_scaled<<<nbC, TPB, 0, stream>>>((const float4*)x, deg, dinv, yb, n8);
    scanB<<<1, 512, 0, stream>>>(bcnt, edge_base, rowoff, NB, E, N);
    passC<<<NB, TPB, 0, stream>>>(ebuck, edge_base, rowoff, csr_src, N);

    int nbL = (N + 3) / 4;
    gcn_layer<<<nbL, TPB, 0, stream>>>(yb, rowoff, csr_src, dinv, w1, b1, hb, N, 1);
    gcn_layer<<<nbL, TPB, 0, stream>>>(hb, rowoff, csr_src, dinv, w2, b2, out, N, 0);
}